// Round 1
// baseline (876.782 us; speedup 1.0000x reference)
//
#include <hip/hip_runtime.h>
#include <stdint.h>

// ---------------------------------------------------------------------------
// QuantLinearNet: y = fq8( fq8(x) @ fq4(W).T + bq )
// Round 4: GEMM untouched (MFMA-bound at its 2-phase structural ceiling).
// Elementwise overhaul: quant_both rewritten to fully-coalesced thread<->float4
// (old layout issued 64B-strided dwordx4 loads touching 64 cache lines per
// instruction); maxabs unrolled x4, finalize unrolled x2 for MLP.
// ---------------------------------------------------------------------------

typedef __attribute__((ext_vector_type(4))) int i32x4;

#define BM 128
#define BN 128
#define BKB 128  // K-bytes (= i8 elements) per tile

__device__ __forceinline__ void async_copy16(const void* g, void* l) {
  __builtin_amdgcn_global_load_lds((const __attribute__((address_space(1))) void*)g,
                                   (__attribute__((address_space(3))) void*)l,
                                   16, 0, 0);
}

__device__ __forceinline__ float wave_max64(float v) {
#pragma unroll
  for (int off = 32; off > 0; off >>= 1) v = fmaxf(v, __shfl_xor(v, off, 64));
  return v;
}

__device__ __forceinline__ float max4(float4 v) {
  return fmaxf(fmaxf(fabsf(v.x), fabsf(v.y)), fmaxf(fabsf(v.z), fabsf(v.w)));
}

// blocks [0, WBLK) reduce W, the rest reduce x. One launch, two atomics.
#define WBLK 1024
__global__ void maxabs_both(const float4* __restrict__ x, int n4x,
                            const float4* __restrict__ w, int n4w,
                            unsigned* __restrict__ scal) {
  const bool isW = (int)blockIdx.x < WBLK;
  const float4* __restrict__ p = isW ? w : x;
  const int n4 = isW ? n4w : n4x;
  const int bid = isW ? blockIdx.x : blockIdx.x - WBLK;
  const int nb = isW ? WBLK : gridDim.x - WBLK;
  const int stride = nb * blockDim.x;

  float m0 = 0.f, m1 = 0.f, m2 = 0.f, m3 = 0.f;
  int i = bid * blockDim.x + threadIdx.x;
  // x: 16 strides/thread -> exactly 4 unrolled iters; W likewise.
  for (; i + 3 * stride < n4; i += 4 * stride) {
    m0 = fmaxf(m0, max4(p[i]));
    m1 = fmaxf(m1, max4(p[i + stride]));
    m2 = fmaxf(m2, max4(p[i + 2 * stride]));
    m3 = fmaxf(m3, max4(p[i + 3 * stride]));
  }
  for (; i < n4; i += stride) m0 = fmaxf(m0, max4(p[i]));
  float m = wave_max64(fmaxf(fmaxf(m0, m1), fmaxf(m2, m3)));

  __shared__ float wm[4];
  if ((threadIdx.x & 63) == 0) wm[threadIdx.x >> 6] = m;
  __syncthreads();
  if (threadIdx.x == 0)
    atomicMax(&scal[isW ? 1 : 0],
              __float_as_uint(fmaxf(fmaxf(wm[0], wm[1]), fmaxf(wm[2], wm[3]))));
}

__device__ __forceinline__ unsigned pack4(float4 v, float inv, float qmax) {
  unsigned b0 = (unsigned)(int)fminf(fmaxf(rintf(v.x * inv), -qmax), qmax) & 0xffu;
  unsigned b1 = (unsigned)(int)fminf(fmaxf(rintf(v.y * inv), -qmax), qmax) & 0xffu;
  unsigned b2 = (unsigned)(int)fminf(fmaxf(rintf(v.z * inv), -qmax), qmax) & 0xffu;
  unsigned b3 = (unsigned)(int)fminf(fmaxf(rintf(v.w * inv), -qmax), qmax) & 0xffu;
  return b0 | (b1 << 8) | (b2 << 16) | (b3 << 24);
}

// fake-quant fp32 -> int8 codes. Fully coalesced: thread i reads float4 i
// (16B/lane, consecutive lanes consecutive addresses) and writes uint32 i
// (4B/lane, 256B/wave contiguous). Word i = elements 4i..4i+3 -> byte layout
// identical to the previous uint4 chunk scheme.
__global__ void quant_both(const float4* __restrict__ x, unsigned* __restrict__ xq, int n4x,
                           const float4* __restrict__ w, unsigned* __restrict__ wq, int n4w,
                           const unsigned* __restrict__ scal) {
  const bool isW = (int)blockIdx.x < WBLK;
  const float4* __restrict__ src = isW ? w : x;
  unsigned* __restrict__ dst = isW ? wq : xq;
  const int n4 = isW ? n4w : n4x;
  const int bid = isW ? blockIdx.x : blockIdx.x - WBLK;
  const int nb = isW ? WBLK : gridDim.x - WBLK;
  const float qmax = isW ? 7.f : 127.f;
  const float inv = qmax / __uint_as_float(scal[isW ? 1 : 0]);
  const int stride = nb * blockDim.x;

  int i = bid * blockDim.x + threadIdx.x;
  for (; i + stride < n4; i += 2 * stride) {
    float4 a = src[i];
    float4 b = src[i + stride];
    dst[i] = pack4(a, inv, qmax);
    dst[i + stride] = pack4(b, inv, qmax);
  }
  if (i < n4) dst[i] = pack4(src[i], inv, qmax);
}

// C[m,n] = sum_k A[m,k]*B[n,k], A/B int8 codes, K-major.
// 16B-chunk XOR swizzle on LDS rows -> 0 bank conflicts (verified round 2).
__global__ __launch_bounds__(256, 4) void gemm_i8(
    const uint8_t* __restrict__ Aq, const uint8_t* __restrict__ Bq,
    const float* __restrict__ bias, float* __restrict__ Out,
    unsigned* __restrict__ scal, int M, int N, int K) {
  __shared__ uint8_t sA[BM * BKB];
  __shared__ uint8_t sB[BN * BKB];
  __shared__ float wred[4];

  const int t = threadIdx.x;
  const int lane = t & 63, wave = t >> 6;
  const int wm = wave >> 1, wn = wave & 1;
  const int quad = lane >> 4, l16 = lane & 15;
  const int bm = blockIdx.y * BM, bn = blockIdx.x * BN;

  i32x4 acc[4][4] = {};

  for (int k0 = 0; k0 < K; k0 += BKB) {
#pragma unroll
    for (int j = 0; j < 4; ++j) {
      const int id = j * 256 + t;          // 16B chunk id in tile (1024 total)
      const int r = id >> 3;               // row (8 chunks/row)
      const int cc = id & 7;               // LDS chunk position in row
      const int gc = (cc ^ (r & 7)) << 4;  // swizzled global byte offset
      async_copy16(Aq + (size_t)(bm + r) * K + k0 + gc, sA + id * 16);
      async_copy16(Bq + (size_t)(bn + r) * K + k0 + gc, sB + id * 16);
    }
    __syncthreads();
#pragma unroll
    for (int kk = 0; kk < 2; ++kk) {  // two K=64 steps per tile
      i32x4 af[4], bf[4];
#pragma unroll
      for (int mt = 0; mt < 4; ++mt) {
        const int row = wm * 64 + mt * 16 + l16;
        const int p = (quad + kk * 4) ^ (row & 7);
        af[mt] = *(const i32x4*)&sA[row * BKB + p * 16];
      }
#pragma unroll
      for (int nt = 0; nt < 4; ++nt) {
        const int row = wn * 64 + nt * 16 + l16;
        const int p = (quad + kk * 4) ^ (row & 7);
        bf[nt] = *(const i32x4*)&sB[row * BKB + p * 16];
      }
#pragma unroll
      for (int mt = 0; mt < 4; ++mt)
#pragma unroll
        for (int nt = 0; nt < 4; ++nt)
          acc[mt][nt] = __builtin_amdgcn_mfma_i32_16x16x64_i8(af[mt], bf[nt], acc[mt][nt], 0, 0, 0);
    }
    __syncthreads();
  }

  // epilogue: t = acc + round(b/s_b); store integer-valued fp32 t; max|t|
  const float s_in = __uint_as_float(scal[0]) / 127.0f;
  const float s_w = __uint_as_float(scal[1]) / 7.0f;
  const float s_b = s_in * s_w;
  float bi[4];
#pragma unroll
  for (int nt = 0; nt < 4; ++nt) {
    const int n = bn + wn * 64 + nt * 16 + l16;
    bi[nt] = rintf(bias[n] / s_b);  // 4 divides/thread, epilogue-only
  }
  float lmax = 0.f;
#pragma unroll
  for (int mt = 0; mt < 4; ++mt) {
#pragma unroll
    for (int r = 0; r < 4; ++r) {
      const int m = bm + wm * 64 + mt * 16 + quad * 4 + r;
      float* orow = Out + (size_t)m * N + bn + wn * 64 + l16;
#pragma unroll
      for (int nt = 0; nt < 4; ++nt) {
        float tv = (float)acc[mt][nt][r] + bi[nt];
        orow[nt * 16] = tv;
        lmax = fmaxf(lmax, fabsf(tv));
      }
    }
  }
  lmax = wave_max64(lmax);
  if (lane == 0) wred[wave] = lmax;
  __syncthreads();
  if (t == 0)
    atomicMax(&scal[2], __float_as_uint(fmaxf(fmaxf(wred[0], wred[1]), fmaxf(wred[2], wred[3]))));
}

__device__ __forceinline__ float4 quantize4(float4 v, float inv, float s_out) {
  v.x = fminf(fmaxf(rintf(v.x * inv), -127.f), 127.f) * s_out;
  v.y = fminf(fmaxf(rintf(v.y * inv), -127.f), 127.f) * s_out;
  v.z = fminf(fmaxf(rintf(v.z * inv), -127.f), 127.f) * s_out;
  v.w = fminf(fmaxf(rintf(v.w * inv), -127.f), 127.f) * s_out;
  return v;
}

__global__ void finalize4(float4* __restrict__ out, int n4, const unsigned* __restrict__ scal) {
  const float s_in = __uint_as_float(scal[0]) / 127.0f;
  const float s_w = __uint_as_float(scal[1]) / 7.0f;
  const float s_b = s_in * s_w;
  const float maxt = __uint_as_float(scal[2]);
  const float s_out = (s_b * maxt) / 127.0f;
  const float inv = 127.0f / maxt;
  const int stride = gridDim.x * blockDim.x;
  int i = blockIdx.x * blockDim.x + threadIdx.x;
  for (; i + stride < n4; i += 2 * stride) {
    float4 a = out[i];
    float4 b = out[i + stride];
    out[i] = quantize4(a, inv, s_out);
    out[i + stride] = quantize4(b, inv, s_out);
  }
  if (i < n4) out[i] = quantize4(out[i], inv, s_out);
}

extern "C" void kernel_launch(void* const* d_in, const int* in_sizes, int n_in,
                              void* d_out, int out_size, void* d_ws, size_t ws_size,
                              hipStream_t stream) {
  const float* x = (const float*)d_in[0];
  const float* W = (const float*)d_in[1];
  const float* b = (const float*)d_in[2];
  float* out = (float*)d_out;

  const int N = in_sizes[2];       // 4096 (H)
  const int K = in_sizes[1] / N;   // 4096 (D)
  const int M = in_sizes[0] / K;   // 16384 (tokens)

  unsigned* scal = (unsigned*)d_ws;
  const size_t OFF = 4096;
  uint8_t* xq = (uint8_t*)d_ws + OFF;  // M*K bytes
  uint8_t* wq = xq + (size_t)M * K;    // N*K bytes

  const int n4x = (M / 4) * K;         // x in float4 units
  const int n4w = (N / 4) * K;         // W in float4 units

  hipMemsetAsync(scal, 0, 16, stream);
  maxabs_both<<<WBLK + 4096, 256, 0, stream>>>((const float4*)x, n4x,
                                               (const float4*)W, n4w, scal);
  quant_both<<<WBLK + 4096, 256, 0, stream>>>((const float4*)x, (unsigned*)xq, n4x,
                                              (const float4*)W, (unsigned*)wq, n4w, scal);

  dim3 grid(N / BN, M / BM);
  gemm_i8<<<grid, 256, 0, stream>>>(xq, wq, b, out, scal, M, N, K);

  finalize4<<<8192, 256, 0, stream>>>((float4*)out, (int)((size_t)M * N / 4), scal);
}